// Round 12
// baseline (221.675 us; speedup 1.0000x reference)
//
#include <hip/hip_runtime.h>
#include <math.h>

#define BATCH 2
#define CIN   256
#define COUT  256
#define HWPIX 4096
#define CKTOT 2304
#define PH    66            // padded feat spatial dim
#define PHW   4356          // 66*66
#define NKG   8             // conv_om K-split

typedef __attribute__((ext_vector_type(8))) short short8;
typedef __attribute__((ext_vector_type(8))) unsigned short ushort8;
typedef __attribute__((ext_vector_type(4))) float float4v;

__device__ __forceinline__ unsigned short f2bf(float f) {
    unsigned u = __float_as_uint(f);
    unsigned r = (u + 0x7FFFu + ((u >> 16) & 1u)) >> 16;   // RNE
    return (unsigned short)r;
}
__device__ __forceinline__ float bf2f(unsigned short h) {
    return __uint_as_float(((unsigned)h) << 16);
}

// ---------------------------------------------------------------------------
// prep: ONE kernel, blockIdx regions (same as r11):
//   [0,2048)      x -> xTh (NHWC, bf16)
//   [2048,4096)   feat -> fh (NHWC, zero-padded 66x66, bf16)
//   [4096,6400)   wpack   (w_dcn -> whi, bf16, A-frag layout)
//   [6400,6688)   wpack_om(w_offset_mask -> wohi, M=32 padded, bf16)
//   [6688,7208)   zero fh borders (both batches)
// ---------------------------------------------------------------------------
__global__ __launch_bounds__(256) void prep_kernel(
    const float* __restrict__ x, const float* __restrict__ feat,
    const float* __restrict__ wdcn, const float* __restrict__ wom,
    unsigned short* __restrict__ xTh,
    unsigned short* __restrict__ fh,
    unsigned short* __restrict__ whi,
    unsigned short* __restrict__ wohi)
{
    const int bid = blockIdx.x;
    const int tid = threadIdx.x;

    if (bid < 4096) {
        const bool isx = bid < 2048;
        const int lb = isx ? bid : bid - 2048;
        const int b  = lb >> 10;
        const int r  = lb & 1023;
        const int pt = r >> 3;       // 128 px tiles of 32
        const int ct = r & 7;        // 8 ch tiles of 32
        __shared__ float t[32][33];
        const int tx = tid & 31, ty = tid >> 5;
        const float* src = isx ? x : feat;
        const float* sb = src + ((size_t)b * 256 + ct * 32) * HWPIX + pt * 32;
#pragma unroll
        for (int i = ty; i < 32; i += 8)
            t[i][tx] = sb[(size_t)i * HWPIX + tx];
        __syncthreads();
        if (isx) {
            unsigned short* ob = xTh + ((size_t)b * HWPIX + pt * 32) * 256 + ct * 32;
#pragma unroll
            for (int i = ty; i < 32; i += 8)
                ob[(size_t)i * 256 + tx] = f2bf(t[tx][i]);
        } else {
#pragma unroll
            for (int i = ty; i < 32; i += 8) {
                int p = pt * 32 + i;
                int row = (p >> 6) + 1, col = (p & 63) + 1;
                fh[((size_t)b * PHW + row * PH + col) * 256 + ct * 32 + tx]
                    = f2bf(t[tx][i]);
            }
        }
    } else if (bid < 6400) {
        int gid = (bid - 4096) * 256 + tid;    // 0..589823
        int cc  = gid & 31;
        int co  = (gid >> 5) & 255;
        int kcb = gid >> 13;
        int k   = kcb >> 3;
        int cb  = kcb & 7;
        float w = wdcn[((size_t)co * 256 + cb * 32 + cc) * 9 + k];
        whi[gid] = f2bf(w);
    } else if (bid < 6688) {
        int gid = (bid - 6400) * 256 + tid;    // 0..73727
        int cc  = gid & 31;
        int co  = (gid >> 5) & 31;
        int kcb = gid >> 10;
        int k   = kcb >> 3;
        int cb  = kcb & 7;
        float w = 0.0f;
        if (co < 27) w = wom[(size_t)co * CKTOT + (cb * 32 + cc) * 9 + k];
        wohi[gid] = f2bf(w);
    } else {
        int idx = (bid - 6688) * 256 + tid;    // < 133120 = 2*260*256 exactly
        int b = idx / 66560;
        int r = idx - b * 66560;
        int pidx = r >> 8;                     // 0..259 border cells
        int c = r & 255;
        int row, col;
        if (pidx < 66)       { row = 0;           col = pidx; }
        else if (pidx < 132) { row = 65;          col = pidx - 66; }
        else if (pidx < 196) { row = pidx - 131;  col = 0; }
        else                 { row = pidx - 195;  col = 65; }
        fh[((size_t)b * PHW + row * PH + col) * 256 + c] = 0;
    }
}

// ---------------------------------------------------------------------------
// conv_om via single-bf16 MFMA, K-split x8; om8[kg][b][27][4096] partials.
// ---------------------------------------------------------------------------
__global__ __launch_bounds__(256) void conv_om_mfma_kernel(
    const unsigned short* __restrict__ fh,     // [2][4356][256] bf16
    const unsigned short* __restrict__ wohi,
    float* __restrict__ om8)                   // [8][2][27][4096]
{
    const int y  = blockIdx.x;     // 0..63
    const int kg = blockIdx.y;     // 0..7
    const int b  = blockIdx.z;
    const int tid = threadIdx.x;
    const int wv  = tid >> 6;
    const int lane = tid & 63;
    const int l15 = lane & 15;
    const int q   = lane >> 4;
    const int xg  = wv * 16 + l15;

    float4v acc[2];
    acc[0] = (float4v)0.0f;
    acc[1] = (float4v)0.0f;

    const unsigned short* fhb = fh + (size_t)b * PHW * 256;

#pragma unroll 3
    for (int i = 0; i < 9; ++i) {
        int kcb = kg * 9 + i;
        int k  = kcb >> 3;
        int cb = kcb & 7;
        size_t s = ((size_t)((y + k / 3) * PH + xg + k % 3)) * 256 + cb * 32 + q * 8;
        short8 bh = *(const short8*)(fhb + s);
        short8 ah0 = *(const short8*)(wohi + ((size_t)kcb * 32 + l15) * 32 + q * 8);
        short8 ah1 = *(const short8*)(wohi + ((size_t)kcb * 32 + 16 + l15) * 32 + q * 8);
        acc[0] = __builtin_amdgcn_mfma_f32_16x16x32_bf16(ah0, bh, acc[0], 0, 0, 0);
        acc[1] = __builtin_amdgcn_mfma_f32_16x16x32_bf16(ah1, bh, acc[1], 0, 0, 0);
    }

    const int p = y * 64 + xg;
    float* ob = om8 + (size_t)(kg * 2 + b) * 27 * HWPIX;
#pragma unroll
    for (int t = 0; t < 2; ++t) {
#pragma unroll
        for (int r = 0; r < 4; ++r) {
            int co = t * 16 + q * 4 + r;
            if (co < 27) ob[co * HWPIX + p] = acc[t][r];
        }
    }
}

// ---------------------------------------------------------------------------
// sample: barrier-free im2col materialization for ONE batch.
// thread = (k, px, cpart): samples 64 channels (cpart*64..+64) at (k,px),
// writes bf16 into V[kcb][px][cc32] (B-fragment-ready layout).
// grid (64 px-tiles, 9 taps); 576 blocks, no LDS, no barriers.
// ---------------------------------------------------------------------------
__global__ __launch_bounds__(256) void sample_kernel(
    const unsigned short* __restrict__ xTh,    // [2][4096][256] bf16
    const float* __restrict__ om8,             // [8][2][27][4096]
    const float* __restrict__ bom,             // [27]
    unsigned short* __restrict__ V,            // [72][4096][32] (this batch)
    int b)
{
    const int tid = threadIdx.x;
    const int k   = blockIdx.y;                // 0..8
    const int px  = blockIdx.x * 64 + (tid >> 2);
    const int cpart = tid & 3;                 // channels cpart*64..+64
    const int y  = px >> 6, xg = px & 63;

    // ---- coords: sum om partials + bias ----
    float dy = bom[2 * k], dx = bom[2 * k + 1], mm = bom[18 + k];
#pragma unroll
    for (int g = 0; g < NKG; ++g) {
        const float* ob = om8 + (size_t)(g * 2 + b) * 27 * HWPIX;
        dy += ob[(2 * k) * HWPIX + px];
        dx += ob[(2 * k + 1) * HWPIX + px];
        mm += ob[(18 + k) * HWPIX + px];
    }
    float ys = (float)(y  - 1 + (k / 3)) + dy;
    float xs = (float)(xg - 1 + (k % 3)) + dx;
    float y0f = floorf(ys), x0f = floorf(xs);
    int y0 = (int)y0f, x0 = (int)x0f;
    float ly = ys - y0f, lx = xs - x0f;
    float m  = 1.0f / (1.0f + expf(-mm));
    bool yv0 = ((unsigned)y0 < 64u), yv1 = ((unsigned)(y0 + 1) < 64u);
    bool xv0 = ((unsigned)x0 < 64u), xv1 = ((unsigned)(x0 + 1) < 64u);
    int i00 = y0 * 64 + x0;
    float w00 = (yv0 && xv0) ? (1.0f - ly) * (1.0f - lx) * m : 0.0f;
    float w01 = (yv0 && xv1) ? (1.0f - ly) * lx * m          : 0.0f;
    float w10 = (yv1 && xv0) ? ly * (1.0f - lx) * m          : 0.0f;
    float w11 = (yv1 && xv1) ? ly * lx * m                   : 0.0f;
    int j00 = (yv0 && xv0) ? i00      : 0;
    int j01 = (yv0 && xv1) ? i00 + 1  : 0;
    int j10 = (yv1 && xv0) ? i00 + 64 : 0;
    int j11 = (yv1 && xv1) ? i00 + 65 : 0;

    const unsigned short* xc = xTh + ((size_t)b << 12) * 256 + cpart * 64;

#pragma unroll 2
    for (int j = 0; j < 8; ++j) {
        int c0 = cpart * 64 + j * 8;
        ushort8 u00 = *(const ushort8*)(xc + (size_t)j00 * 256 + j * 8);
        ushort8 u01 = *(const ushort8*)(xc + (size_t)j01 * 256 + j * 8);
        ushort8 u10 = *(const ushort8*)(xc + (size_t)j10 * 256 + j * 8);
        ushort8 u11 = *(const ushort8*)(xc + (size_t)j11 * 256 + j * 8);
        unsigned hv[4];
#pragma unroll
        for (int jj = 0; jj < 4; ++jj) {
            float va = w00 * bf2f(u00[2 * jj])     + w01 * bf2f(u01[2 * jj])
                     + w10 * bf2f(u10[2 * jj])     + w11 * bf2f(u11[2 * jj]);
            float vb = w00 * bf2f(u00[2 * jj + 1]) + w01 * bf2f(u01[2 * jj + 1])
                     + w10 * bf2f(u10[2 * jj + 1]) + w11 * bf2f(u11[2 * jj + 1]);
            hv[jj] = (unsigned)f2bf(va) | ((unsigned)f2bf(vb) << 16);
        }
        int cb = c0 >> 5, cc = c0 & 31;
        int kcb = k * 8 + cb;
        *(uint4*)&V[((size_t)kcb * HWPIX + px) * 32 + cc]
            = make_uint4(hv[0], hv[1], hv[2], hv[3]);
    }
}

// ---------------------------------------------------------------------------
// gemm: barrier-free, LDS-free MFMA GEMM for ONE batch.
// C[co 256, px 4096] = whi[256,2304] x V[2304,4096] + bias.
// Block = 64co x 64px (4 waves, each 64co x 16px). Both A- and B-fragments
// load directly from L2 as fully-coalesced 1KB wave transactions.
// ---------------------------------------------------------------------------
__global__ __launch_bounds__(256) void gemm_kernel(
    const unsigned short* __restrict__ V,      // [72][4096][32] (this batch)
    const unsigned short* __restrict__ whi,    // [72][256][32]
    const float* __restrict__ bdcn,            // [256]
    float* __restrict__ out,                   // [2][256][4096]
    int b)
{
    const int tid = threadIdx.x;
    const int coT = blockIdx.x;    // 0..3
    const int pxT = blockIdx.y;    // 0..63
    const int w   = tid >> 6;
    const int lane = tid & 63;
    const int l15 = lane & 15;
    const int q   = lane >> 4;
    const int px0 = pxT * 64 + w * 16;

    float4v acc[4];
#pragma unroll
    for (int t = 0; t < 4; ++t) acc[t] = (float4v)0.0f;

#pragma unroll 3
    for (int kcb = 0; kcb < 72; ++kcb) {
        short8 bf = *(const short8*)(V + ((size_t)kcb * HWPIX + px0 + l15) * 32 + q * 8);
        size_t ab = ((size_t)kcb * 256 + coT * 64 + l15) * 32 + q * 8;
        short8 a0 = *(const short8*)(whi + ab);
        short8 a1 = *(const short8*)(whi + ab + 16 * 32);
        short8 a2 = *(const short8*)(whi + ab + 32 * 32);
        short8 a3 = *(const short8*)(whi + ab + 48 * 32);
        acc[0] = __builtin_amdgcn_mfma_f32_16x16x32_bf16(a0, bf, acc[0], 0, 0, 0);
        acc[1] = __builtin_amdgcn_mfma_f32_16x16x32_bf16(a1, bf, acc[1], 0, 0, 0);
        acc[2] = __builtin_amdgcn_mfma_f32_16x16x32_bf16(a2, bf, acc[2], 0, 0, 0);
        acc[3] = __builtin_amdgcn_mfma_f32_16x16x32_bf16(a3, bf, acc[3], 0, 0, 0);
    }

    // ---- epilogue (D: row co = q*4+r, col px = l15) ----
#pragma unroll
    for (int t = 0; t < 4; ++t) {
#pragma unroll
        for (int r = 0; r < 4; ++r) {
            int co = coT * 64 + t * 16 + q * 4 + r;
            out[(((size_t)b * COUT + co) << 12) + px0 + l15] = acc[t][r] + bdcn[co];
        }
    }
}

// ---------------------------------------------------------------------------
extern "C" void kernel_launch(void* const* d_in, const int* in_sizes, int n_in,
                              void* d_out, int out_size, void* d_ws, size_t ws_size,
                              hipStream_t stream)
{
    const float* x    = (const float*)d_in[0];
    const float* feat = (const float*)d_in[1];
    const float* wom  = (const float*)d_in[2];
    const float* bom  = (const float*)d_in[3];
    const float* wdcn = (const float*)d_in[4];
    const float* bdcn = (const float*)d_in[5];
    float* out = (float*)d_out;

    // workspace layout (~36 MB, all 16B-aligned)
    float* om8           = (float*)d_ws;                         // 8*2*27*4096 f32
    unsigned short* whi  = (unsigned short*)(om8 + (size_t)NKG * 2 * 27 * HWPIX);
    unsigned short* wohi = whi + (size_t)CKTOT * 256;            // 73728
    unsigned short* xTh  = wohi + 73728;                         // 2*4096*256
    unsigned short* fh   = xTh + (size_t)2 * HWPIX * 256;        // 2*4356*256
    unsigned short* V    = fh + (size_t)2 * PHW * 256;           // 72*4096*32 (one batch)

    prep_kernel<<<7208, 256, 0, stream>>>(x, feat, wdcn, wom, xTh, fh,
                                          whi, wohi);

    dim3 gco(64, NKG, 2);
    conv_om_mfma_kernel<<<gco, 256, 0, stream>>>(fh, wohi, om8);

    for (int b = 0; b < 2; ++b) {
        dim3 gs(64, 9);
        sample_kernel<<<gs, 256, 0, stream>>>(xTh, om8, bom, V, b);
        dim3 gg(4, 64);
        gemm_kernel<<<gg, 256, 0, stream>>>(V, whi, bdcn, out, b);
    }
}

// Round 13
// 133.940 us; speedup vs baseline: 1.6550x; 1.6550x over previous
//
#include <hip/hip_runtime.h>
#include <math.h>

#define BATCH 2
#define CIN   256
#define COUT  256
#define COFF  256
#define HWPIX 4096
#define CKTOT 2304
#define VSTR  40            // V row stride in shorts (80 B)
#define VSLOT (288 * VSTR)  // one chunk buffer (23 KB)
#define PH    66            // padded feat spatial dim
#define PHW   4356          // 66*66
#define NKG   12            // conv_om K-split

typedef __attribute__((ext_vector_type(8))) short short8;
typedef __attribute__((ext_vector_type(8))) unsigned short ushort8;
typedef __attribute__((ext_vector_type(4))) float float4v;

__device__ __forceinline__ unsigned short f2bf(float f) {
    unsigned u = __float_as_uint(f);
    unsigned r = (u + 0x7FFFu + ((u >> 16) & 1u)) >> 16;   // RNE
    return (unsigned short)r;
}
__device__ __forceinline__ float bf2f(unsigned short h) {
    return __uint_as_float(((unsigned)h) << 16);
}

// ---------------------------------------------------------------------------
// prep: ONE kernel, blockIdx regions (same as r11):
//   [0,2048)      x -> xTh (NHWC, bf16)
//   [2048,4096)   feat -> fh (NHWC, zero-padded 66x66, bf16)
//   [4096,6400)   wpack   (w_dcn -> whi, bf16, A-frag layout)
//   [6400,6688)   wpack_om(w_offset_mask -> wohi, M=32 padded, bf16)
//   [6688,7208)   zero fh borders (both batches)
// ---------------------------------------------------------------------------
__global__ __launch_bounds__(256) void prep_kernel(
    const float* __restrict__ x, const float* __restrict__ feat,
    const float* __restrict__ wdcn, const float* __restrict__ wom,
    unsigned short* __restrict__ xTh,
    unsigned short* __restrict__ fh,
    unsigned short* __restrict__ whi,
    unsigned short* __restrict__ wohi)
{
    const int bid = blockIdx.x;
    const int tid = threadIdx.x;

    if (bid < 4096) {
        const bool isx = bid < 2048;
        const int lb = isx ? bid : bid - 2048;
        const int b  = lb >> 10;
        const int r  = lb & 1023;
        const int pt = r >> 3;       // 128 px tiles of 32
        const int ct = r & 7;        // 8 ch tiles of 32
        __shared__ float t[32][33];
        const int tx = tid & 31, ty = tid >> 5;
        const float* src = isx ? x : feat;
        const float* sb = src + ((size_t)b * 256 + ct * 32) * HWPIX + pt * 32;
#pragma unroll
        for (int i = ty; i < 32; i += 8)
            t[i][tx] = sb[(size_t)i * HWPIX + tx];
        __syncthreads();
        if (isx) {
            unsigned short* ob = xTh + ((size_t)b * HWPIX + pt * 32) * 256 + ct * 32;
#pragma unroll
            for (int i = ty; i < 32; i += 8)
                ob[(size_t)i * 256 + tx] = f2bf(t[tx][i]);
        } else {
#pragma unroll
            for (int i = ty; i < 32; i += 8) {
                int p = pt * 32 + i;
                int row = (p >> 6) + 1, col = (p & 63) + 1;
                fh[((size_t)b * PHW + row * PH + col) * 256 + ct * 32 + tx]
                    = f2bf(t[tx][i]);
            }
        }
    } else if (bid < 6400) {
        int gid = (bid - 4096) * 256 + tid;    // 0..589823
        int cc  = gid & 31;
        int co  = (gid >> 5) & 255;
        int kcb = gid >> 13;
        int k   = kcb >> 3;
        int cb  = kcb & 7;
        float w = wdcn[((size_t)co * 256 + cb * 32 + cc) * 9 + k];
        whi[gid] = f2bf(w);
    } else if (bid < 6688) {
        int gid = (bid - 6400) * 256 + tid;    // 0..73727
        int cc  = gid & 31;
        int co  = (gid >> 5) & 31;
        int kcb = gid >> 10;
        int k   = kcb >> 3;
        int cb  = kcb & 7;
        float w = 0.0f;
        if (co < 27) w = wom[(size_t)co * CKTOT + (cb * 32 + cc) * 9 + k];
        wohi[gid] = f2bf(w);
    } else {
        int idx = (bid - 6688) * 256 + tid;    // < 133120 = 2*260*256 exactly
        int b = idx / 66560;
        int r = idx - b * 66560;
        int pidx = r >> 8;                     // 0..259 border cells
        int c = r & 255;
        int row, col;
        if (pidx < 66)       { row = 0;           col = pidx; }
        else if (pidx < 132) { row = 65;          col = pidx - 66; }
        else if (pidx < 196) { row = pidx - 131;  col = 0; }
        else                 { row = pidx - 195;  col = 65; }
        fh[((size_t)b * PHW + row * PH + col) * 256 + c] = 0;
    }
}

// ---------------------------------------------------------------------------
// conv_om via single-bf16 MFMA, K-split x12; om12[kg][b][27][4096] partials.
// ---------------------------------------------------------------------------
__global__ __launch_bounds__(256) void conv_om_mfma_kernel(
    const unsigned short* __restrict__ fh,     // [2][4356][256] bf16
    const unsigned short* __restrict__ wohi,
    float* __restrict__ om12)                  // [12][2][27][4096]
{
    const int y  = blockIdx.x;     // 0..63
    const int kg = blockIdx.y;     // 0..11
    const int b  = blockIdx.z;
    const int tid = threadIdx.x;
    const int wv  = tid >> 6;
    const int lane = tid & 63;
    const int l15 = lane & 15;
    const int q   = lane >> 4;
    const int xg  = wv * 16 + l15;

    float4v acc[2];
    acc[0] = (float4v)0.0f;
    acc[1] = (float4v)0.0f;

    const unsigned short* fhb = fh + (size_t)b * PHW * 256;

#pragma unroll 3
    for (int i = 0; i < 6; ++i) {
        int kcb = kg * 6 + i;
        int k  = kcb >> 3;
        int cb = kcb & 7;
        size_t s = ((size_t)((y + k / 3) * PH + xg + k % 3)) * 256 + cb * 32 + q * 8;
        short8 bh = *(const short8*)(fhb + s);
        short8 ah0 = *(const short8*)(wohi + ((size_t)kcb * 32 + l15) * 32 + q * 8);
        short8 ah1 = *(const short8*)(wohi + ((size_t)kcb * 32 + 16 + l15) * 32 + q * 8);
        acc[0] = __builtin_amdgcn_mfma_f32_16x16x32_bf16(ah0, bh, acc[0], 0, 0, 0);
        acc[1] = __builtin_amdgcn_mfma_f32_16x16x32_bf16(ah1, bh, acc[1], 0, 0, 0);
    }

    const int p = y * 64 + xg;
    float* ob = om12 + (size_t)(kg * 2 + b) * 27 * HWPIX;
#pragma unroll
    for (int t = 0; t < 2; ++t) {
#pragma unroll
        for (int r = 0; r < 4; ++r) {
            int co = t * 16 + q * 4 + r;
            if (co < 27) ob[co * HWPIX + p] = acc[t][r];
        }
    }
}

// ---------------------------------------------------------------------------
// dcn v10: r11 structure with double-buffered V and ONE barrier per chunk.
// In each barrier region: stage(cb+1)->bufB first (program order), then
// mfma(cb)<-bufA — compiler free to interleave; occupancy is grid-capped at
// 2 blocks/CU so VGPR growth is harmless. Tile 128co x 32px, grid (128,2,2).
// ---------------------------------------------------------------------------
__global__ __launch_bounds__(256) void dcn_mfma_kernel(
    const unsigned short* __restrict__ xTh,    // [2][4096][256] bf16
    const float* __restrict__ om12,            // [12][2][27][4096]
    const unsigned short* __restrict__ whi,    // [72][256][32] bf16
    const float* __restrict__ bom,             // [27]
    const float* __restrict__ bdcn,            // [256]
    float* __restrict__ out)                   // [2][256][4096]
{
    const int tid = threadIdx.x;
    const int y   = blockIdx.x >> 1;           // 0..63
    const int xh  = blockIdx.x & 1;            // 0..1 (32-px halves)
    const int cog = blockIdx.y;                // 0..1 (co halves)
    const int b   = blockIdx.z;

    __shared__ float4 s_wt[288];               // masked bilinear weights
    __shared__ int4   s_ix[288];               // clamped corner indices
    __shared__ unsigned short V[2 * VSLOT];    // double-buffered B tiles

    // ---- prologue: sum 12 om partials + bias; bilinear weights + indices ----
    for (int idx = tid; idx < 288; idx += 256) {
        int k   = idx >> 5;
        int pxl = idx & 31;
        int xg  = xh * 32 + pxl;
        int p   = y * 64 + xg;
        float dy = bom[2 * k], dx = bom[2 * k + 1], mm = bom[18 + k];
#pragma unroll
        for (int g = 0; g < NKG; ++g) {
            const float* ob = om12 + (size_t)(g * 2 + b) * 27 * HWPIX;
            dy += ob[(2 * k) * HWPIX + p];
            dx += ob[(2 * k + 1) * HWPIX + p];
            mm += ob[(18 + k) * HWPIX + p];
        }
        float ys = (float)(y  - 1 + (k / 3)) + dy;
        float xs = (float)(xg - 1 + (k % 3)) + dx;
        float y0f = floorf(ys), x0f = floorf(xs);
        int y0 = (int)y0f, x0 = (int)x0f;
        float ly = ys - y0f, lx = xs - x0f;
        float m  = 1.0f / (1.0f + expf(-mm));
        bool yv0 = ((unsigned)y0 < 64u), yv1 = ((unsigned)(y0 + 1) < 64u);
        bool xv0 = ((unsigned)x0 < 64u), xv1 = ((unsigned)(x0 + 1) < 64u);
        int i00 = y0 * 64 + x0;
        float4 wt;
        int4 ix;
        wt.x = (yv0 && xv0) ? (1.0f - ly) * (1.0f - lx) * m : 0.0f;
        wt.y = (yv0 && xv1) ? (1.0f - ly) * lx * m          : 0.0f;
        wt.z = (yv1 && xv0) ? ly * (1.0f - lx) * m          : 0.0f;
        wt.w = (yv1 && xv1) ? ly * lx * m                   : 0.0f;
        ix.x = (yv0 && xv0) ? i00      : 0;
        ix.y = (yv0 && xv1) ? i00 + 1  : 0;
        ix.z = (yv1 && xv0) ? i00 + 64 : 0;
        ix.w = (yv1 && xv1) ? i00 + 65 : 0;
        s_wt[idx] = wt;
        s_ix[idx] = ix;
    }
    __syncthreads();

    const int w    = tid >> 6;     // wave -> co base cog*128 + w*32
    const int lane = tid & 63;
    const int l15  = lane & 15;
    const int q    = lane >> 4;

    // staging map: cg = tid&3 (8 ch), spx = (tid>>2)&31, tapg = tid>>7
    const int cg   = tid & 3;
    const int spx  = (tid >> 2) & 31;
    const int tapg = tid >> 7;     // 0: taps 0,2,4,6,8  1: taps 1,3,5,7

    float4v acc[2][2];
#pragma unroll
    for (int t = 0; t < 2; ++t)
#pragma unroll
        for (int p = 0; p < 2; ++p) acc[t][p] = (float4v)0.0f;

    const unsigned short* xb = xTh + ((size_t)b << 12) * 256;

    // ---- stage chunk 0 into V[0] ----
    {
        const unsigned short* xc = xb + 0 * 32 + cg * 8;
#pragma unroll 3
        for (int j = 0; j < 5; ++j) {
            int k = 2 * j + tapg;
            if (k > 8) break;
            int cidx = k * 32 + spx;
            float4 wt = s_wt[cidx];
            int4   ix = s_ix[cidx];
            ushort8 u00 = *(const ushort8*)(xc + (size_t)ix.x * 256);
            ushort8 u01 = *(const ushort8*)(xc + (size_t)ix.y * 256);
            ushort8 u10 = *(const ushort8*)(xc + (size_t)ix.z * 256);
            ushort8 u11 = *(const ushort8*)(xc + (size_t)ix.w * 256);
            unsigned hv[4];
#pragma unroll
            for (int jj = 0; jj < 4; ++jj) {
                float va = wt.x * bf2f(u00[2 * jj])     + wt.y * bf2f(u01[2 * jj])
                         + wt.z * bf2f(u10[2 * jj])     + wt.w * bf2f(u11[2 * jj]);
                float vb = wt.x * bf2f(u00[2 * jj + 1]) + wt.y * bf2f(u01[2 * jj + 1])
                         + wt.z * bf2f(u10[2 * jj + 1]) + wt.w * bf2f(u11[2 * jj + 1]);
                hv[jj] = (unsigned)f2bf(va) | ((unsigned)f2bf(vb) << 16);
            }
            *(uint4*)&V[cidx * VSTR + cg * 8] = make_uint4(hv[0], hv[1], hv[2], hv[3]);
        }
    }
    __syncthreads();

    for (int cb = 0; cb < 8; ++cb) {
        const unsigned short* Vc = V + (cb & 1) * VSLOT;

        // ---- stage chunk cb+1 into the other buffer (issued first) ----
        if (cb < 7) {
            unsigned short* Vd = V + ((cb + 1) & 1) * VSLOT;
            const unsigned short* xc = xb + (cb + 1) * 32 + cg * 8;
#pragma unroll 3
            for (int j = 0; j < 5; ++j) {
                int k = 2 * j + tapg;
                if (k > 8) break;
                int cidx = k * 32 + spx;
                float4 wt = s_wt[cidx];
                int4   ix = s_ix[cidx];
                ushort8 u00 = *(const ushort8*)(xc + (size_t)ix.x * 256);
                ushort8 u01 = *(const ushort8*)(xc + (size_t)ix.y * 256);
                ushort8 u10 = *(const ushort8*)(xc + (size_t)ix.z * 256);
                ushort8 u11 = *(const ushort8*)(xc + (size_t)ix.w * 256);
                unsigned hv[4];
#pragma unroll
                for (int jj = 0; jj < 4; ++jj) {
                    float va = wt.x * bf2f(u00[2 * jj])     + wt.y * bf2f(u01[2 * jj])
                             + wt.z * bf2f(u10[2 * jj])     + wt.w * bf2f(u11[2 * jj]);
                    float vb = wt.x * bf2f(u00[2 * jj + 1]) + wt.y * bf2f(u01[2 * jj + 1])
                             + wt.z * bf2f(u10[2 * jj + 1]) + wt.w * bf2f(u11[2 * jj + 1]);
                    hv[jj] = (unsigned)f2bf(va) | ((unsigned)f2bf(vb) << 16);
                }
                *(uint4*)&Vd[cidx * VSTR + cg * 8] = make_uint4(hv[0], hv[1], hv[2], hv[3]);
            }
        }

        // ---- MFMA chain for chunk cb from Vc (same barrier region) ----
#pragma unroll 3
        for (int k = 0; k < 9; ++k) {
            const int kcb = k * 8 + cb;
            size_t base = ((size_t)kcb * 256 + cog * 128 + w * 32 + l15) * 32 + q * 8;
            short8 ah0 = *(const short8*)(whi + base);
            short8 ah1 = *(const short8*)(whi + base + 16 * 32);
            short8 bh0 = *(const short8*)&Vc[(k * 32 + l15) * VSTR + q * 8];
            short8 bh1 = *(const short8*)&Vc[(k * 32 + 16 + l15) * VSTR + q * 8];
            acc[0][0] = __builtin_amdgcn_mfma_f32_16x16x32_bf16(ah0, bh0, acc[0][0], 0, 0, 0);
            acc[0][1] = __builtin_amdgcn_mfma_f32_16x16x32_bf16(ah0, bh1, acc[0][1], 0, 0, 0);
            acc[1][0] = __builtin_amdgcn_mfma_f32_16x16x32_bf16(ah1, bh0, acc[1][0], 0, 0, 0);
            acc[1][1] = __builtin_amdgcn_mfma_f32_16x16x32_bf16(ah1, bh1, acc[1][1], 0, 0, 0);
        }
        __syncthreads();
    }

    // ---- epilogue: plain stores (D: row co = q*4+r, col px = l15) ----
#pragma unroll
    for (int t = 0; t < 2; ++t) {
#pragma unroll
        for (int r = 0; r < 4; ++r) {
            int co = cog * 128 + w * 32 + t * 16 + q * 4 + r;
            float bias = bdcn[co];
#pragma unroll
            for (int p = 0; p < 2; ++p) {
                int px = xh * 32 + p * 16 + l15;
                out[(((size_t)b * COUT + co) << 12) + y * 64 + px]
                    = acc[t][p][r] + bias;
            }
        }
    }
}

// ---------------------------------------------------------------------------
extern "C" void kernel_launch(void* const* d_in, const int* in_sizes, int n_in,
                              void* d_out, int out_size, void* d_ws, size_t ws_size,
                              hipStream_t stream)
{
    const float* x    = (const float*)d_in[0];
    const float* feat = (const float*)d_in[1];
    const float* wom  = (const float*)d_in[2];
    const float* bom  = (const float*)d_in[3];
    const float* wdcn = (const float*)d_in[4];
    const float* bdcn = (const float*)d_in[5];
    float* out = (float*)d_out;

    // workspace layout (all 16B-aligned)
    float* om12          = (float*)d_ws;                         // 12*2*27*4096 f32
    unsigned short* whi  = (unsigned short*)(om12 + (size_t)NKG * 2 * 27 * HWPIX);
    unsigned short* wohi = whi + (size_t)CKTOT * 256;            // 73728
    unsigned short* xTh  = wohi + 73728;                         // 2*4096*256
    unsigned short* fh   = xTh + (size_t)2 * HWPIX * 256;        // 2*4356*256

    prep_kernel<<<7208, 256, 0, stream>>>(x, feat, wdcn, wom, xTh, fh,
                                          whi, wohi);

    dim3 gco(64, NKG, 2);
    conv_om_mfma_kernel<<<gco, 256, 0, stream>>>(fh, wohi, om12);

    dim3 grid(128, 2, 2);
    dcn_mfma_kernel<<<grid, 256, 0, stream>>>(xTh, om12, whi, bom, bdcn, out);
}

// Round 14
// 132.796 us; speedup vs baseline: 1.6693x; 1.0086x over previous
//
#include <hip/hip_runtime.h>
#include <math.h>

#define BATCH 2
#define CIN   256
#define COUT  256
#define COFF  256
#define HWPIX 4096
#define CKTOT 2304
#define VSTR  40            // V row stride in shorts (80 B)
#define PH    66            // padded feat spatial dim
#define PHW   4356          // 66*66
#define NKG   12            // conv_om K-split

typedef __attribute__((ext_vector_type(8))) short short8;
typedef __attribute__((ext_vector_type(8))) unsigned short ushort8;
typedef __attribute__((ext_vector_type(4))) float float4v;

__device__ __forceinline__ unsigned short f2bf(float f) {
    unsigned u = __float_as_uint(f);
    unsigned r = (u + 0x7FFFu + ((u >> 16) & 1u)) >> 16;   // RNE
    return (unsigned short)r;
}
__device__ __forceinline__ float bf2f(unsigned short h) {
    return __uint_as_float(((unsigned)h) << 16);
}

// ---------------------------------------------------------------------------
// prep: ONE kernel, blockIdx regions:
//   [0,2048)      x -> xTh (NHWC, bf16)
//   [2048,4096)   feat -> fh (NHWC, zero-padded 66x66, bf16)
//   [4096,6400)   wpack   (w_dcn -> whi, bf16, A-frag layout)
//   [6400,6688)   wpack_om(w_offset_mask -> wohi, M=32 padded, bf16)
//   [6688,7208)   zero fh borders (both batches)
//   [7208,9256)   zero out (float4) — needed by dcn's atomic epilogue
// ---------------------------------------------------------------------------
__global__ __launch_bounds__(256) void prep_kernel(
    const float* __restrict__ x, const float* __restrict__ feat,
    const float* __restrict__ wdcn, const float* __restrict__ wom,
    unsigned short* __restrict__ xTh,
    unsigned short* __restrict__ fh,
    unsigned short* __restrict__ whi,
    unsigned short* __restrict__ wohi,
    float* __restrict__ out)
{
    const int bid = blockIdx.x;
    const int tid = threadIdx.x;

    if (bid < 4096) {
        const bool isx = bid < 2048;
        const int lb = isx ? bid : bid - 2048;
        const int b  = lb >> 10;
        const int r  = lb & 1023;
        const int pt = r >> 3;       // 128 px tiles of 32
        const int ct = r & 7;        // 8 ch tiles of 32
        __shared__ float t[32][33];
        const int tx = tid & 31, ty = tid >> 5;
        const float* src = isx ? x : feat;
        const float* sb = src + ((size_t)b * 256 + ct * 32) * HWPIX + pt * 32;
#pragma unroll
        for (int i = ty; i < 32; i += 8)
            t[i][tx] = sb[(size_t)i * HWPIX + tx];
        __syncthreads();
        if (isx) {
            unsigned short* ob = xTh + ((size_t)b * HWPIX + pt * 32) * 256 + ct * 32;
#pragma unroll
            for (int i = ty; i < 32; i += 8)
                ob[(size_t)i * 256 + tx] = f2bf(t[tx][i]);
        } else {
#pragma unroll
            for (int i = ty; i < 32; i += 8) {
                int p = pt * 32 + i;
                int row = (p >> 6) + 1, col = (p & 63) + 1;
                fh[((size_t)b * PHW + row * PH + col) * 256 + ct * 32 + tx]
                    = f2bf(t[tx][i]);
            }
        }
    } else if (bid < 6400) {
        int gid = (bid - 4096) * 256 + tid;    // 0..589823
        int cc  = gid & 31;
        int co  = (gid >> 5) & 255;
        int kcb = gid >> 13;
        int k   = kcb >> 3;
        int cb  = kcb & 7;
        float w = wdcn[((size_t)co * 256 + cb * 32 + cc) * 9 + k];
        whi[gid] = f2bf(w);
    } else if (bid < 6688) {
        int gid = (bid - 6400) * 256 + tid;    // 0..73727
        int cc  = gid & 31;
        int co  = (gid >> 5) & 31;
        int kcb = gid >> 10;
        int k   = kcb >> 3;
        int cb  = kcb & 7;
        float w = 0.0f;
        if (co < 27) w = wom[(size_t)co * CKTOT + (cb * 32 + cc) * 9 + k];
        wohi[gid] = f2bf(w);
    } else if (bid < 7208) {
        int idx = (bid - 6688) * 256 + tid;    // < 133120 = 2*260*256 exactly
        int b = idx / 66560;
        int r = idx - b * 66560;
        int pidx = r >> 8;                     // 0..259 border cells
        int c = r & 255;
        int row, col;
        if (pidx < 66)       { row = 0;           col = pidx; }
        else if (pidx < 132) { row = 65;          col = pidx - 66; }
        else if (pidx < 196) { row = pidx - 131;  col = 0; }
        else                 { row = pidx - 195;  col = 65; }
        fh[((size_t)b * PHW + row * PH + col) * 256 + c] = 0;
    } else {
        int idx = (bid - 7208) * 256 + tid;    // < 524288 float4 exactly
        ((float4*)out)[idx] = make_float4(0.f, 0.f, 0.f, 0.f);
    }
}

// ---------------------------------------------------------------------------
// conv_om via single-bf16 MFMA, K-split x12; om12[kg][b][27][4096] partials.
// ---------------------------------------------------------------------------
__global__ __launch_bounds__(256) void conv_om_mfma_kernel(
    const unsigned short* __restrict__ fh,     // [2][4356][256] bf16
    const unsigned short* __restrict__ wohi,
    float* __restrict__ om12)                  // [12][2][27][4096]
{
    const int y  = blockIdx.x;     // 0..63
    const int kg = blockIdx.y;     // 0..11
    const int b  = blockIdx.z;
    const int tid = threadIdx.x;
    const int wv  = tid >> 6;
    const int lane = tid & 63;
    const int l15 = lane & 15;
    const int q   = lane >> 4;
    const int xg  = wv * 16 + l15;

    float4v acc[2];
    acc[0] = (float4v)0.0f;
    acc[1] = (float4v)0.0f;

    const unsigned short* fhb = fh + (size_t)b * PHW * 256;

#pragma unroll 3
    for (int i = 0; i < 6; ++i) {
        int kcb = kg * 6 + i;
        int k  = kcb >> 3;
        int cb = kcb & 7;
        size_t s = ((size_t)((y + k / 3) * PH + xg + k % 3)) * 256 + cb * 32 + q * 8;
        short8 bh = *(const short8*)(fhb + s);
        short8 ah0 = *(const short8*)(wohi + ((size_t)kcb * 32 + l15) * 32 + q * 8);
        short8 ah1 = *(const short8*)(wohi + ((size_t)kcb * 32 + 16 + l15) * 32 + q * 8);
        acc[0] = __builtin_amdgcn_mfma_f32_16x16x32_bf16(ah0, bh, acc[0], 0, 0, 0);
        acc[1] = __builtin_amdgcn_mfma_f32_16x16x32_bf16(ah1, bh, acc[1], 0, 0, 0);
    }

    const int p = y * 64 + xg;
    float* ob = om12 + (size_t)(kg * 2 + b) * 27 * HWPIX;
#pragma unroll
    for (int t = 0; t < 2; ++t) {
#pragma unroll
        for (int r = 0; r < 4; ++r) {
            int co = t * 16 + q * 4 + r;
            if (co < 27) ob[co * HWPIX + p] = acc[t][r];
        }
    }
}

// ---------------------------------------------------------------------------
// dcn v11: r11 structure + kg-split x2 for occupancy. Tile 128co x 32px,
// each block covers cb in {kg*4 .. kg*4+3}; grid (128, 4, 2) = 1024 blocks
// = 4 blocks/CU (LDS 32.25 KB, VGPR capped by launch_bounds). Epilogue
// accumulates via fp32 atomicAdd into pre-zeroed out (2-way contention).
// ---------------------------------------------------------------------------
__global__ __launch_bounds__(256, 4) void dcn_mfma_kernel(
    const unsigned short* __restrict__ xTh,    // [2][4096][256] bf16
    const float* __restrict__ om12,            // [12][2][27][4096]
    const unsigned short* __restrict__ whi,    // [72][256][32] bf16
    const float* __restrict__ bom,             // [27]
    const float* __restrict__ bdcn,            // [256]
    float* __restrict__ out)                   // [2][256][4096] pre-zeroed
{
    const int tid = threadIdx.x;
    const int y   = blockIdx.x >> 1;           // 0..63
    const int xh  = blockIdx.x & 1;            // 0..1 (32-px halves)
    const int cog = blockIdx.y >> 1;           // 0..1 (co halves)
    const int kg  = blockIdx.y & 1;            // 0..1 (cb halves)
    const int b   = blockIdx.z;

    __shared__ float4 s_wt[288];               // masked bilinear weights
    __shared__ int4   s_ix[288];               // clamped corner indices
    __shared__ unsigned short V[288 * VSTR];   // B tiles [k*32+px][ch]

    // ---- prologue: sum 12 om partials + bias; bilinear weights + indices ----
    for (int idx = tid; idx < 288; idx += 256) {
        int k   = idx >> 5;
        int pxl = idx & 31;
        int xg  = xh * 32 + pxl;
        int p   = y * 64 + xg;
        float dy = bom[2 * k], dx = bom[2 * k + 1], mm = bom[18 + k];
#pragma unroll
        for (int g = 0; g < NKG; ++g) {
            const float* ob = om12 + (size_t)(g * 2 + b) * 27 * HWPIX;
            dy += ob[(2 * k) * HWPIX + p];
            dx += ob[(2 * k + 1) * HWPIX + p];
            mm += ob[(18 + k) * HWPIX + p];
        }
        float ys = (float)(y  - 1 + (k / 3)) + dy;
        float xs = (float)(xg - 1 + (k % 3)) + dx;
        float y0f = floorf(ys), x0f = floorf(xs);
        int y0 = (int)y0f, x0 = (int)x0f;
        float ly = ys - y0f, lx = xs - x0f;
        float m  = 1.0f / (1.0f + expf(-mm));
        bool yv0 = ((unsigned)y0 < 64u), yv1 = ((unsigned)(y0 + 1) < 64u);
        bool xv0 = ((unsigned)x0 < 64u), xv1 = ((unsigned)(x0 + 1) < 64u);
        int i00 = y0 * 64 + x0;
        float4 wt;
        int4 ix;
        wt.x = (yv0 && xv0) ? (1.0f - ly) * (1.0f - lx) * m : 0.0f;
        wt.y = (yv0 && xv1) ? (1.0f - ly) * lx * m          : 0.0f;
        wt.z = (yv1 && xv0) ? ly * (1.0f - lx) * m          : 0.0f;
        wt.w = (yv1 && xv1) ? ly * lx * m                   : 0.0f;
        ix.x = (yv0 && xv0) ? i00      : 0;
        ix.y = (yv0 && xv1) ? i00 + 1  : 0;
        ix.z = (yv1 && xv0) ? i00 + 64 : 0;
        ix.w = (yv1 && xv1) ? i00 + 65 : 0;
        s_wt[idx] = wt;
        s_ix[idx] = ix;
    }
    __syncthreads();

    const int w    = tid >> 6;     // wave -> co base cog*128 + w*32
    const int lane = tid & 63;
    const int l15  = lane & 15;
    const int q    = lane >> 4;

    // staging map: cg = tid&3 (8 ch), spx = (tid>>2)&31, tapg = tid>>7
    const int cg   = tid & 3;
    const int spx  = (tid >> 2) & 31;
    const int tapg = tid >> 7;     // 0: taps 0,2,4,6,8  1: taps 1,3,5,7

    float4v acc[2][2];
#pragma unroll
    for (int t = 0; t < 2; ++t)
#pragma unroll
        for (int p = 0; p < 2; ++p) acc[t][p] = (float4v)0.0f;

    const unsigned short* xb = xTh + ((size_t)b << 12) * 256;

    for (int cbl = 0; cbl < 4; ++cbl) {
        const int cb = kg * 4 + cbl;

        // ---- stage: ~4.5 taps x 32 px x 8 ch per thread (16B gathers) ----
        {
            const unsigned short* xc = xb + cb * 32 + cg * 8;
#pragma unroll 3
            for (int j = 0; j < 5; ++j) {
                int k = 2 * j + tapg;
                if (k > 8) break;
                int cidx = k * 32 + spx;
                float4 wt = s_wt[cidx];
                int4   ix = s_ix[cidx];
                ushort8 u00 = *(const ushort8*)(xc + (size_t)ix.x * 256);
                ushort8 u01 = *(const ushort8*)(xc + (size_t)ix.y * 256);
                ushort8 u10 = *(const ushort8*)(xc + (size_t)ix.z * 256);
                ushort8 u11 = *(const ushort8*)(xc + (size_t)ix.w * 256);
                unsigned hv[4];
#pragma unroll
                for (int jj = 0; jj < 4; ++jj) {
                    float va = wt.x * bf2f(u00[2 * jj])     + wt.y * bf2f(u01[2 * jj])
                             + wt.z * bf2f(u10[2 * jj])     + wt.w * bf2f(u11[2 * jj]);
                    float vb = wt.x * bf2f(u00[2 * jj + 1]) + wt.y * bf2f(u01[2 * jj + 1])
                             + wt.z * bf2f(u10[2 * jj + 1]) + wt.w * bf2f(u11[2 * jj + 1]);
                    hv[jj] = (unsigned)f2bf(va) | ((unsigned)f2bf(vb) << 16);
                }
                *(uint4*)&V[cidx * VSTR + cg * 8]
                    = make_uint4(hv[0], hv[1], hv[2], hv[3]);
            }
        }
        __syncthreads();

        // ---- 9 MFMA chunks on this cb: 2 A-loads + 2 ds + 4 MFMA each ----
#pragma unroll 3
        for (int k = 0; k < 9; ++k) {
            const int kcb = k * 8 + cb;
            size_t base = ((size_t)kcb * 256 + cog * 128 + w * 32 + l15) * 32 + q * 8;
            short8 ah0 = *(const short8*)(whi + base);
            short8 ah1 = *(const short8*)(whi + base + 16 * 32);
            short8 bh0 = *(const short8*)&V[(k * 32 + l15) * VSTR + q * 8];
            short8 bh1 = *(const short8*)&V[(k * 32 + 16 + l15) * VSTR + q * 8];
            acc[0][0] = __builtin_amdgcn_mfma_f32_16x16x32_bf16(ah0, bh0, acc[0][0], 0, 0, 0);
            acc[0][1] = __builtin_amdgcn_mfma_f32_16x16x32_bf16(ah0, bh1, acc[0][1], 0, 0, 0);
            acc[1][0] = __builtin_amdgcn_mfma_f32_16x16x32_bf16(ah1, bh0, acc[1][0], 0, 0, 0);
            acc[1][1] = __builtin_amdgcn_mfma_f32_16x16x32_bf16(ah1, bh1, acc[1][1], 0, 0, 0);
        }
        __syncthreads();
    }

    // ---- epilogue: atomic accumulate (kg partials); kg0 adds bias ----
#pragma unroll
    for (int t = 0; t < 2; ++t) {
#pragma unroll
        for (int r = 0; r < 4; ++r) {
            int co = cog * 128 + w * 32 + t * 16 + q * 4 + r;
            float bias = (kg == 0) ? bdcn[co] : 0.0f;
#pragma unroll
            for (int p = 0; p < 2; ++p) {
                int px = xh * 32 + p * 16 + l15;
                atomicAdd(&out[(((size_t)b * COUT + co) << 12) + y * 64 + px],
                          acc[t][p][r] + bias);
            }
        }
    }
}

// ---------------------------------------------------------------------------
extern "C" void kernel_launch(void* const* d_in, const int* in_sizes, int n_in,
                              void* d_out, int out_size, void* d_ws, size_t ws_size,
                              hipStream_t stream)
{
    const float* x    = (const float*)d_in[0];
    const float* feat = (const float*)d_in[1];
    const float* wom  = (const float*)d_in[2];
    const float* bom  = (const float*)d_in[3];
    const float* wdcn = (const float*)d_in[4];
    const float* bdcn = (const float*)d_in[5];
    float* out = (float*)d_out;

    // workspace layout (all 16B-aligned)
    float* om12          = (float*)d_ws;                         // 12*2*27*4096 f32
    unsigned short* whi  = (unsigned short*)(om12 + (size_t)NKG * 2 * 27 * HWPIX);
    unsigned short* wohi = whi + (size_t)CKTOT * 256;            // 73728
    unsigned short* xTh  = wohi + 73728;                         // 2*4096*256
    unsigned short* fh   = xTh + (size_t)2 * HWPIX * 256;        // 2*4356*256

    prep_kernel<<<9256, 256, 0, stream>>>(x, feat, wdcn, wom, xTh, fh,
                                          whi, wohi, out);

    dim3 gco(64, NKG, 2);
    conv_om_mfma_kernel<<<gco, 256, 0, stream>>>(fh, wohi, om12);

    dim3 grid(128, 4, 2);
    dcn_mfma_kernel<<<grid, 256, 0, stream>>>(xTh, om12, whi, bom, bdcn, out);
}